// Round 3
// baseline (52.254 us; speedup 1.0000x reference)
//
#include <hip/hip_runtime.h>

#define HH   48
#define WW   96
#define CC   256
#define RRAD 4
#define DD   9
#define DD2  81
#define PP   10
#define HWSZ (HH * WW)
#define ROWB 512                    // bytes per bf16 channel row (256*2)
#define ZOFF ((unsigned)HWSZ * ROWB) // zero page offset from f2tb base

typedef __attribute__((ext_vector_type(8))) short short8v;  // 8 bf16 (4 VGPRs)
typedef __attribute__((ext_vector_type(4))) float f32x4;

__device__ __forceinline__ unsigned bf16rne(float f) {      // RNE f32->bf16 bits
  unsigned u = __float_as_uint(f);
  return (u + 0x7FFFu + ((u >> 16) & 1u)) >> 16;
}

// ---------------- kernel 1: (C,H,W) fp32 -> (H*W, C) bf16 ----------------
// blockIdx.y: 0 = f1 -> f1tb, 1 = f2 -> f2tb. Block 0 also zeroes the zero page.
__global__ __launch_bounds__(256) void transpose_to_bf16(
    const float* __restrict__ f1, const float* __restrict__ f2,
    char* __restrict__ f2tb, char* __restrict__ f1tb, char* __restrict__ zpage) {
  __shared__ float tile[64][65];
  const float* src = (blockIdx.y == 0) ? f1 : f2;
  char* dst = (blockIdx.y == 0) ? f1tb : f2tb;

  const int tid = threadIdx.x;
  if (blockIdx.x == 0 && blockIdx.y == 0) {   // zero the 1 KB zero page
    ((unsigned*)zpage)[tid] = 0u;             // 256 * 4 B = 1024 B
  }

  const int tiles_p = HWSZ / 64;              // 72
  const int bc = blockIdx.x / tiles_p;        // channel tile 0..3
  const int bp = blockIdx.x % tiles_p;        // pixel tile 0..71
  const int c0 = bc * 64, p0 = bp * 64;

#pragma unroll
  for (int k = 0; k < 16; k++) {
    int idx = k * 256 + tid;
    int cl = idx >> 6, pl = idx & 63;         // coalesced over pixels
    tile[cl][pl] = src[(size_t)(c0 + cl) * HWSZ + p0 + pl];
  }
  __syncthreads();
#pragma unroll
  for (int k = 0; k < 8; k++) {               // pack 2 channels -> 4 B stores
    int idx = k * 256 + tid;
    int pl = idx >> 5, cp = idx & 31;
    unsigned lo = bf16rne(tile[2 * cp][pl]);
    unsigned hi = bf16rne(tile[2 * cp + 1][pl]);
    *(unsigned*)(dst + (size_t)(p0 + pl) * ROWB + (size_t)c0 * 2 + cp * 4) =
        lo | (hi << 16);
  }
}

// ---------------- kernel 2: MFMA correlation + DAP, one block per pixel ----------------
__global__ __launch_bounds__(256) void corr_main(
    const char* __restrict__ f2tb, const char* __restrict__ f1tb,
    const float* __restrict__ coords, const float* __restrict__ w_dap,
    float* __restrict__ out) {
  __shared__ float dots[112];
  __shared__ unsigned rowoff[112];
  __shared__ float corrs[DD2];
  __shared__ float partial[3][DD2];

  const int p = blockIdx.x;                   // pixel h*W+w
  const int tid = threadIdx.x;

  const float cx = coords[p];
  const float cy = coords[HWSZ + p];
  const float fxf = floorf(cx), fyf = floorf(cy);
  const float fx = cx - fxf, fy = cy - fyf;   // fractional weights shared by all 81 offsets
  const int xb = (int)fxf - RRAD;
  const int yb = (int)fyf - RRAD;

  // patch-row byte offsets (invalid / pad rows -> zero page)
  if (tid < 112) {
    unsigned off = ZOFF;
    if (tid < 100) {
      int yy = tid / 10, xx = tid - yy * 10;
      int gy = yb + yy, gx = xb + xx;
      if (gx >= 0 && gx < WW && gy >= 0 && gy < HH)
        off = (unsigned)(gy * WW + gx) * ROWB;
    }
    rowoff[tid] = off;
  }

  const int lane = tid & 63, wid = tid >> 6;
  const int hi = lane >> 4, lo = lane & 15;

  // B fragments: f1 vector, k = hi*8 + j within each ktile (col = lo, all cols same)
  const char* f1b = f1tb + (size_t)p * ROWB + hi * 16;
  short8v bfrag[8];
#pragma unroll
  for (int kt = 0; kt < 8; kt++) bfrag[kt] = *(const short8v*)(f1b + kt * 64);

  __syncthreads();

  // A: patch rows; lane reads row (mtile*16 + lo), bytes hi*16 + kt*64
  const char* Ab = f2tb + hi * 16;
  for (int m = wid; m < 7; m += 4) {
    const char* rp = Ab + rowoff[m * 16 + lo];
    short8v a0 = *(const short8v*)(rp);
    short8v a1 = *(const short8v*)(rp + 64);
    short8v a2 = *(const short8v*)(rp + 128);
    short8v a3 = *(const short8v*)(rp + 192);
    short8v a4 = *(const short8v*)(rp + 256);
    short8v a5 = *(const short8v*)(rp + 320);
    short8v a6 = *(const short8v*)(rp + 384);
    short8v a7 = *(const short8v*)(rp + 448);
    f32x4 acc = {0.f, 0.f, 0.f, 0.f};
    acc = __builtin_amdgcn_mfma_f32_16x16x32_bf16(a0, bfrag[0], acc, 0, 0, 0);
    acc = __builtin_amdgcn_mfma_f32_16x16x32_bf16(a1, bfrag[1], acc, 0, 0, 0);
    acc = __builtin_amdgcn_mfma_f32_16x16x32_bf16(a2, bfrag[2], acc, 0, 0, 0);
    acc = __builtin_amdgcn_mfma_f32_16x16x32_bf16(a3, bfrag[3], acc, 0, 0, 0);
    acc = __builtin_amdgcn_mfma_f32_16x16x32_bf16(a4, bfrag[4], acc, 0, 0, 0);
    acc = __builtin_amdgcn_mfma_f32_16x16x32_bf16(a5, bfrag[5], acc, 0, 0, 0);
    acc = __builtin_amdgcn_mfma_f32_16x16x32_bf16(a6, bfrag[6], acc, 0, 0, 0);
    acc = __builtin_amdgcn_mfma_f32_16x16x32_bf16(a7, bfrag[7], acc, 0, 0, 0);
    // D: col = lo, row = hi*4 + j; keep col 0 only
    if (lo == 0) {
      const int rb = m * 16 + hi * 4;
      dots[rb + 0] = acc[0];
      dots[rb + 1] = acc[1];
      dots[rb + 2] = acc[2];
      dots[rb + 3] = acc[3];
    }
  }
  __syncthreads();

  // 81 bilinear combines; d = i*9 + j (i = x-offset idx, j = y-offset idx)
  if (tid < DD2) {
    const int i = tid / DD, j = tid - i * DD;
    const float d00 = dots[j * PP + i];
    const float d01 = dots[j * PP + i + 1];
    const float d10 = dots[(j + 1) * PP + i];
    const float d11 = dots[(j + 1) * PP + i + 1];
    const float c = (1.f - fy) * ((1.f - fx) * d00 + fx * d01) +
                    fy * ((1.f - fx) * d10 + fx * d11);
    corrs[tid] = c * 0.0625f;                 // 1/sqrt(256)
  }
  __syncthreads();

  // DAP: out[o] = sum_d w_dap[o,d] * corrs[d]
  if (tid < 243) {
    const int o = tid % DD2, chunk = tid / DD2;
    const int d0 = chunk * 27;
    float acc = 0.f;
#pragma unroll
    for (int d = 0; d < 27; d++) acc += w_dap[o * DD2 + d0 + d] * corrs[d0 + d];
    partial[chunk][o] = acc;
  }
  __syncthreads();
  if (tid < DD2) {
    out[(size_t)tid * HWSZ + p] = partial[0][tid] + partial[1][tid] + partial[2][tid];
  }
}

extern "C" void kernel_launch(void* const* d_in, const int* in_sizes, int n_in,
                              void* d_out, int out_size, void* d_ws, size_t ws_size,
                              hipStream_t stream) {
  const float* f1     = (const float*)d_in[0];
  const float* f2     = (const float*)d_in[1];
  const float* coords = (const float*)d_in[2];
  const float* w_dap  = (const float*)d_in[3];
  float* out = (float*)d_out;

  // ws layout: [f2tb: HWSZ*512 B][zpage: 1024 B][f1tb: HWSZ*512 B]
  char* f2tb  = (char*)d_ws;
  char* zpage = f2tb + (size_t)HWSZ * ROWB;
  char* f1tb  = zpage + 1024;

  dim3 tgrid((CC / 64) * (HWSZ / 64), 2);
  transpose_to_bf16<<<tgrid, 256, 0, stream>>>(f1, f2, f2tb, f1tb, zpage);

  corr_main<<<dim3(HWSZ), 256, 0, stream>>>(f2tb, f1tb, coords, w_dap, out);
}

// Round 4
// 46.683 us; speedup vs baseline: 1.1193x; 1.1193x over previous
//
#include <hip/hip_runtime.h>

#define HH   48
#define WW   96
#define CC   256
#define RRAD 4
#define DD   9
#define DD2  81
#define PP   10
#define HWSZ (HH * WW)
#define ROWB 512                    // bytes per bf16 channel row (256*2)
#define PROWS 100                   // patch rows (10x10)
#define PCHUNKS (PROWS * 32)        // 16B chunks in patch

typedef __attribute__((ext_vector_type(8))) short short8v;  // 8 bf16 (4 VGPRs)
typedef __attribute__((ext_vector_type(4))) float f32x4;

__device__ __forceinline__ unsigned bf16rne(float f) {      // RNE f32->bf16 bits
  unsigned u = __float_as_uint(f);
  return (u + 0x7FFFu + ((u >> 16) & 1u)) >> 16;
}

// ---------------- kernel 1: (C,H,W) fp32 -> (H*W, C) bf16 ----------------
__global__ __launch_bounds__(256) void transpose_to_bf16(
    const float* __restrict__ f1, const float* __restrict__ f2,
    char* __restrict__ f2tb, char* __restrict__ f1tb) {
  __shared__ float tile[64][65];
  const float* src = (blockIdx.y == 0) ? f1 : f2;
  char* dst = (blockIdx.y == 0) ? f1tb : f2tb;

  const int tid = threadIdx.x;
  const int tiles_p = HWSZ / 64;              // 72
  const int bc = blockIdx.x / tiles_p;        // channel tile 0..3
  const int bp = blockIdx.x % tiles_p;        // pixel tile 0..71
  const int c0 = bc * 64, p0 = bp * 64;

#pragma unroll
  for (int k = 0; k < 16; k++) {
    int idx = k * 256 + tid;
    int cl = idx >> 6, pl = idx & 63;         // coalesced over pixels
    tile[cl][pl] = src[(size_t)(c0 + cl) * HWSZ + p0 + pl];
  }
  __syncthreads();
#pragma unroll
  for (int k = 0; k < 8; k++) {               // pack 2 channels -> 4 B stores
    int idx = k * 256 + tid;
    int pl = idx >> 5, cp = idx & 31;
    unsigned lo = bf16rne(tile[2 * cp][pl]);
    unsigned hi = bf16rne(tile[2 * cp + 1][pl]);
    *(unsigned*)(dst + (size_t)(p0 + pl) * ROWB + (size_t)c0 * 2 + cp * 4) =
        lo | (hi << 16);
  }
}

// ---------------- kernel 2: LDS-staged MFMA correlation + DAP ----------------
__global__ __launch_bounds__(256) void corr_main(
    const char* __restrict__ f2tb, const char* __restrict__ f1tb,
    const float* __restrict__ coords, const float* __restrict__ w_dap,
    float* __restrict__ out) {
  __shared__ __align__(16) char patch[PROWS * ROWB];  // 51200 B, XOR-swizzled
  __shared__ unsigned rowoff[PROWS];
  __shared__ float dots[112];
  __shared__ float corrs[DD2];
  float* partial = (float*)patch;             // aliases patch (dead after MFMA)

  const int p = blockIdx.x;                   // pixel h*W+w
  const int tid = threadIdx.x;

  const float cx = coords[p];
  const float cy = coords[HWSZ + p];
  const float fxf = floorf(cx), fyf = floorf(cy);
  const float fx = cx - fxf, fy = cy - fyf;   // fractional weights shared by all 81 offsets
  const int xb = (int)fxf - RRAD;
  const int yb = (int)fyf - RRAD;

  // per-patch-row source byte offsets (invalid -> sentinel, zero-filled in LDS)
  if (tid < PROWS) {
    int yy = tid / 10, xx = tid - yy * 10;
    int gy = yb + yy, gx = xb + xx;
    rowoff[tid] = (gx >= 0 && gx < WW && gy >= 0 && gy < HH)
                      ? (unsigned)(gy * WW + gx) * ROWB : 0xFFFFFFFFu;
  }

  const int lane = tid & 63, wid = tid >> 6;
  const int hi = lane >> 4, lo = lane & 15;

  // B fragments: f1 vector (same for all 16 cols); k = hi*8 + j within ktile
  const char* f1b = f1tb + (size_t)p * ROWB + hi * 16;
  short8v bfrag[8];
#pragma unroll
  for (int kt = 0; kt < 8; kt++) bfrag[kt] = *(const short8v*)(f1b + kt * 64);

  __syncthreads();

  // stage patch: coalesced global reads -> swizzled ds_write_b128
#pragma unroll
  for (int i = 0; i < 13; i++) {
    int chunk = tid + i * 256;
    if (chunk < PCHUNKS) {
      int row = chunk >> 5;                   // 32 chunks per 512B row
      int w16 = chunk & 31;
      unsigned off = rowoff[row];
      float4 v = {0.f, 0.f, 0.f, 0.f};
      if (off != 0xFFFFFFFFu)
        v = *(const float4*)(f2tb + off + w16 * 16);
      *(float4*)(patch + row * ROWB + ((w16 * 16) ^ ((row & 7) << 4))) = v;
    }
  }
  __syncthreads();

  // 7 m-tiles of 16 rows; fragments from swizzled LDS
  for (int m = wid; m < 7; m += 4) {
    int row = m * 16 + lo;
    row = row > 99 ? 99 : row;                // tile 6 tail: duplicate row, discarded
    const char* rp = patch + row * ROWB;
    const int swz = (row & 7) << 4;
    short8v a[8];
#pragma unroll
    for (int kt = 0; kt < 8; kt++)
      a[kt] = *(const short8v*)(rp + ((hi * 16 + kt * 64) ^ swz));
    f32x4 acc = {0.f, 0.f, 0.f, 0.f};
#pragma unroll
    for (int kt = 0; kt < 8; kt++)
      acc = __builtin_amdgcn_mfma_f32_16x16x32_bf16(a[kt], bfrag[kt], acc, 0, 0, 0);
    // D: col = lo, row = hi*4 + j; keep col 0 only
    if (lo == 0) {
      const int rb = m * 16 + hi * 4;
      dots[rb + 0] = acc[0];
      dots[rb + 1] = acc[1];
      dots[rb + 2] = acc[2];
      dots[rb + 3] = acc[3];
    }
  }
  __syncthreads();

  // 81 bilinear combines; d = i*9 + j (i = x-offset idx, j = y-offset idx)
  if (tid < DD2) {
    const int i = tid / DD, j = tid - i * DD;
    const float d00 = dots[j * PP + i];
    const float d01 = dots[j * PP + i + 1];
    const float d10 = dots[(j + 1) * PP + i];
    const float d11 = dots[(j + 1) * PP + i + 1];
    const float c = (1.f - fy) * ((1.f - fx) * d00 + fx * d01) +
                    fy * ((1.f - fx) * d10 + fx * d11);
    corrs[tid] = c * 0.0625f;                 // 1/sqrt(256)
  }
  __syncthreads();

  // DAP: out[o] = sum_d w_dap[o,d] * corrs[d]; partial aliases dead patch
  if (tid < 243) {
    const int o = tid % DD2, chunk = tid / DD2;
    const int d0 = chunk * 27;
    float acc = 0.f;
#pragma unroll
    for (int d = 0; d < 27; d++) acc += w_dap[o * DD2 + d0 + d] * corrs[d0 + d];
    partial[chunk * DD2 + o] = acc;
  }
  __syncthreads();
  if (tid < DD2) {
    out[(size_t)tid * HWSZ + p] =
        partial[tid] + partial[DD2 + tid] + partial[2 * DD2 + tid];
  }
}

extern "C" void kernel_launch(void* const* d_in, const int* in_sizes, int n_in,
                              void* d_out, int out_size, void* d_ws, size_t ws_size,
                              hipStream_t stream) {
  const float* f1     = (const float*)d_in[0];
  const float* f2     = (const float*)d_in[1];
  const float* coords = (const float*)d_in[2];
  const float* w_dap  = (const float*)d_in[3];
  float* out = (float*)d_out;

  // ws layout: [f2tb: HWSZ*512 B][f1tb: HWSZ*512 B]
  char* f2tb = (char*)d_ws;
  char* f1tb = f2tb + (size_t)HWSZ * ROWB;

  dim3 tgrid((CC / 64) * (HWSZ / 64), 2);
  transpose_to_bf16<<<tgrid, 256, 0, stream>>>(f1, f2, f2tb, f1tb);

  corr_main<<<dim3(HWSZ), 256, 0, stream>>>(f2tb, f1tb, coords, w_dap, out);
}

// Round 5
// 37.981 us; speedup vs baseline: 1.3758x; 1.2291x over previous
//
#include <hip/hip_runtime.h>

#define HH   48
#define WW   96
#define CC   256
#define RRAD 4
#define DD   9
#define DD2  81
#define PP   10
#define HWSZ (HH * WW)              // 4608
#define NROWP 4616                  // padded row count for chunk-major f2 (row 4608 = zeros)
#define ROWB 512                    // bytes per bf16 channel row (256*2), f1 layout

typedef __attribute__((ext_vector_type(8))) short short8v;  // 8 bf16 (4 VGPRs)
typedef __attribute__((ext_vector_type(4))) float f32x4;

__device__ __forceinline__ unsigned bf16rne(float f) {      // RNE f32->bf16 bits
  unsigned u = __float_as_uint(f);
  return (u + 0x7FFFu + ((u >> 16) & 1u)) >> 16;
}

// ---------------- kernel 1: fp32 (C,H,W) -> bf16, two layouts ----------------
// y==0: f1 -> f1tb pixel-major [pixel][256ch]   (512 B rows, for B-fragment broadcast)
// y==1: f2 -> f2c  chunk-major [ch/8][pixel]    (16 B elems; A-gathers hit runs of
//        consecutive pixels -> contiguous segments). Row 4608 of every chunk = zeros.
__global__ __launch_bounds__(256) void transpose_to_bf16(
    const float* __restrict__ f1, const float* __restrict__ f2,
    char* __restrict__ f2c, char* __restrict__ f1tb) {
  __shared__ float tile[64][65];
  const int tid = threadIdx.x;
  const int isf2 = blockIdx.y;
  const float* src = isf2 ? f2 : f1;

  const int tiles_p = HWSZ / 64;              // 72
  const int bc = blockIdx.x / tiles_p;        // channel tile 0..3
  const int bp = blockIdx.x % tiles_p;        // pixel tile 0..71
  const int c0 = bc * 64, p0 = bp * 64;

  if (isf2 && blockIdx.x == 0 && tid < 128) { // zero row 4608 of each chunk
    int c = tid >> 2, w = tid & 3;
    *(unsigned*)(f2c + ((size_t)c * NROWP + 4608) * 16 + w * 4) = 0u;
  }

#pragma unroll
  for (int k = 0; k < 16; k++) {
    int idx = k * 256 + tid;
    int cl = idx >> 6, pl = idx & 63;         // coalesced over pixels
    tile[cl][pl] = src[(size_t)(c0 + cl) * HWSZ + p0 + pl];
  }
  __syncthreads();

  if (isf2) {
    // 8 chunks x 64 pixels; each thread packs 8 channels -> 16 B, coalesced over pl
#pragma unroll
    for (int k = 0; k < 2; k++) {
      int idx = k * 256 + tid;
      int cc = idx >> 6, pl = idx & 63;
      unsigned w[4];
#pragma unroll
      for (int j = 0; j < 4; j++) {
        unsigned lo = bf16rne(tile[cc * 8 + 2 * j][pl]);
        unsigned hi = bf16rne(tile[cc * 8 + 2 * j + 1][pl]);
        w[j] = lo | (hi << 16);
      }
      float4 v = {__uint_as_float(w[0]), __uint_as_float(w[1]),
                  __uint_as_float(w[2]), __uint_as_float(w[3])};
      *(float4*)(f2c + ((size_t)(c0 / 8 + cc) * NROWP + p0 + pl) * 16) = v;
    }
  } else {
#pragma unroll
    for (int k = 0; k < 8; k++) {             // pack 2 channels -> 4 B stores
      int idx = k * 256 + tid;
      int pl = idx >> 5, cp = idx & 31;
      unsigned lo = bf16rne(tile[2 * cp][pl]);
      unsigned hi = bf16rne(tile[2 * cp + 1][pl]);
      *(unsigned*)(f1tb + (size_t)(p0 + pl) * ROWB + (size_t)c0 * 2 + cp * 4) =
          lo | (hi << 16);
    }
  }
}

// ---------------- kernel 2: direct-gather MFMA correlation + DAP ----------------
// __launch_bounds__(256, 4): min 4 waves/EU -> VGPR cap 128 so bfrag[8]+a[8] stay
// resident and all gathers are in flight (the VGPR=32 default serialized everything).
__global__ __launch_bounds__(256, 4) void corr_main(
    const char* __restrict__ f2c, const char* __restrict__ f1tb,
    const float* __restrict__ coords, const float* __restrict__ w_dap,
    float* __restrict__ out) {
  __shared__ unsigned rowoff[112];            // patch-row -> image-row (4608 = zero row)
  __shared__ float dots[112];
  __shared__ float corrs[DD2];
  __shared__ float partial[3][DD2];

  const int p = blockIdx.x;                   // pixel h*W+w
  const int tid = threadIdx.x;

  const float cx = coords[p];
  const float cy = coords[HWSZ + p];
  const float fxf = floorf(cx), fyf = floorf(cy);
  const float fx = cx - fxf, fy = cy - fyf;   // fractional weights shared by all 81 offsets
  const int xb = (int)fxf - RRAD;
  const int yb = (int)fyf - RRAD;

  if (tid < 112) {
    unsigned grow = 4608u;                    // zero row
    if (tid < 100) {
      int yy = tid / 10, xx = tid - yy * 10;
      int gy = yb + yy, gx = xb + xx;
      if (gx >= 0 && gx < WW && gy >= 0 && gy < HH) grow = (unsigned)(gy * WW + gx);
    }
    rowoff[tid] = grow;
  }

  const int lane = tid & 63, wid = tid >> 6;
  const int hi = lane >> 4, lo = lane & 15;

  // B fragments: f1 vector (same for all 16 cols); k = hi*8 + j within ktile kt
  const char* f1b = f1tb + (size_t)p * ROWB + hi * 16;
  short8v bfrag[8];
#pragma unroll
  for (int kt = 0; kt < 8; kt++) bfrag[kt] = *(const short8v*)(f1b + kt * 64);

  __syncthreads();

  // 7 m-tiles of 16 patch rows; A gathered straight from chunk-major global
#pragma unroll
  for (int mi = 0; mi < 2; mi++) {
    const int m = wid + mi * 4;
    if (m < 7) {
      const unsigned grow = rowoff[m * 16 + lo];
      short8v a[8];
#pragma unroll
      for (int kt = 0; kt < 8; kt++)
        a[kt] = *(const short8v*)(f2c + ((size_t)(hi + 4 * kt) * NROWP + grow) * 16);
      f32x4 acc = {0.f, 0.f, 0.f, 0.f};
#pragma unroll
      for (int kt = 0; kt < 8; kt++)
        acc = __builtin_amdgcn_mfma_f32_16x16x32_bf16(a[kt], bfrag[kt], acc, 0, 0, 0);
      // D: col = lo, row = hi*4 + j; keep col 0 only
      if (lo == 0) {
        const int rb = m * 16 + hi * 4;
        dots[rb + 0] = acc[0];
        dots[rb + 1] = acc[1];
        dots[rb + 2] = acc[2];
        dots[rb + 3] = acc[3];
      }
    }
  }
  __syncthreads();

  // 81 bilinear combines; d = i*9 + j (i = x-offset idx, j = y-offset idx)
  if (tid < DD2) {
    const int i = tid / DD, j = tid - i * DD;
    const float d00 = dots[j * PP + i];
    const float d01 = dots[j * PP + i + 1];
    const float d10 = dots[(j + 1) * PP + i];
    const float d11 = dots[(j + 1) * PP + i + 1];
    const float c = (1.f - fy) * ((1.f - fx) * d00 + fx * d01) +
                    fy * ((1.f - fx) * d10 + fx * d11);
    corrs[tid] = c * 0.0625f;                 // 1/sqrt(256)
  }
  __syncthreads();

  // DAP: out[o] = sum_d w_dap[o,d] * corrs[d]
  if (tid < 243) {
    const int o = tid % DD2, chunk = tid / DD2;
    const int d0 = chunk * 27;
    float acc = 0.f;
#pragma unroll
    for (int d = 0; d < 27; d++) acc += w_dap[o * DD2 + d0 + d] * corrs[d0 + d];
    partial[chunk][o] = acc;
  }
  __syncthreads();
  if (tid < DD2) {
    out[(size_t)tid * HWSZ + p] =
        partial[0][tid] + partial[1][tid] + partial[2][tid];
  }
}

extern "C" void kernel_launch(void* const* d_in, const int* in_sizes, int n_in,
                              void* d_out, int out_size, void* d_ws, size_t ws_size,
                              hipStream_t stream) {
  const float* f1     = (const float*)d_in[0];
  const float* f2     = (const float*)d_in[1];
  const float* coords = (const float*)d_in[2];
  const float* w_dap  = (const float*)d_in[3];
  float* out = (float*)d_out;

  // ws layout: [f2c: 32*NROWP*16 B][f1tb: HWSZ*512 B]
  char* f2c  = (char*)d_ws;
  char* f1tb = f2c + (size_t)32 * NROWP * 16;

  dim3 tgrid((CC / 64) * (HWSZ / 64), 2);
  transpose_to_bf16<<<tgrid, 256, 0, stream>>>(f1, f2, f2c, f1tb);

  corr_main<<<dim3(HWSZ), 256, 0, stream>>>(f2c, f1tb, coords, w_dap, out);
}